// Round 18
// baseline (540.668 us; speedup 1.0000x reference)
//
#include <hip/hip_runtime.h>

typedef unsigned short u16;
typedef unsigned int   u32;
typedef __attribute__((ext_vector_type(8))) short short8;
typedef __attribute__((ext_vector_type(4))) float f32x4;
typedef __attribute__((ext_vector_type(4))) u16  u16x4;

#define DI __device__ __forceinline__

DI float b2f(u16 v){ return __builtin_bit_cast(float, (u32)v << 16); }
DI u16 f2b(float f){ u32 u = __builtin_bit_cast(u32, f); return (u16)((u + 0x7fffu + ((u >> 16) & 1u)) >> 16); }
DI float lrelu(float v){ return v > 0.f ? v : 0.01f * v; }

// direct global->LDS DMA, 16 B per lane (dest must be lane-contiguous)
DI void gload_lds16(const void* g, void* l){
  __builtin_amdgcn_global_load_lds((const __attribute__((address_space(1))) void*)g,
                                   (__attribute__((address_space(3))) void*)l, 16, 0, 0);
}

// ---------------- prep: zero BN accumulators + f32->bf16 cvt + conv repack -
// Conv weights in MFMA-FRAGMENT-TILED layout (R10: coalesced wave loads).
__global__ __launch_bounds__(256)
void prep(float* __restrict__ partA,
          const float* __restrict__ trees, u16* __restrict__ Tb,
          const float* __restrict__ w1, u16* __restrict__ Wb1,
          const float* __restrict__ w2, u16* __restrict__ Wb2,
          const float* __restrict__ w3, u16* __restrict__ Wb3,
          const float* __restrict__ w4, u16* __restrict__ Wb4,
          const float* __restrict__ cw1, u16* __restrict__ Wr1,
          const float* __restrict__ cw2, u16* __restrict__ Wr2,
          const float* __restrict__ cw3, u16* __restrict__ Wr3)
{
  int loc = blockIdx.x*256 + threadIdx.x;
  if (loc < 10880){ partA[loc] = 0.f; return; }
  loc -= 10880;
  {
    const float* in = nullptr; u16* out = nullptr;
    if      (loc < 32768){ in = trees; out = Tb; }
    else if ((loc -= 32768) < 1024){ in = w1; out = Wb1; }
    else if ((loc -= 1024) < 4096){ in = w2; out = Wb2; }
    else if ((loc -= 4096) < 65536){ in = w3; out = Wb3; }
    else if ((loc -= 65536) < 1048576){ in = w4; out = Wb4; }
    else { loc -= 1048576; goto repack; }
    float4 v = ((const float4*)in)[loc];
    u16x4 o; o[0]=f2b(v.x); o[1]=f2b(v.y); o[2]=f2b(v.z); o[3]=f2b(v.w);
    *(u16x4*)(out + (size_t)loc*4) = o;
    return;
  }
repack:
  {
    const float* w; u16* wr; int C, lgC;
    if      (loc < 24576){ w = cw1; wr = Wr1; C = 64;  lgC = 6; }
    else if ((loc -= 24576) < 98304){ w = cw2; wr = Wr2; C = 128; lgC = 7; }
    else if ((loc -= 98304) < 393216){ w = cw3; wr = Wr3; C = 256; lgC = 8; }
    else return;
    int R   = 3*C;
    int nkb = R >> 5;                 // R/32
    int ci   = loc & 7;
    int lane = (loc >> 3) & 63;
    int blk  = loc >> 9;
    int o_tile = blk / nkb;
    int kbi    = blk - o_tile*nkb;
    int o  = o_tile*16 + (lane & 15);
    int ch = kbi*32 + (lane >> 4)*8 + ci;
    int k  = ch >> lgC;
    int c  = ch & (C-1);
    wr[loc] = f2b(w[(size_t)o*R + c*3 + k]);
  }
}

// ---------------- GEMM (NT): Y[m*YS+n] = A[M,K] * W[N,K]^T, f32 out --------
// YS: output row stride in floats (gemm4 writes per-sample d_out slices).
// Staging: B always via global_load_lds; A via DMA when !APPLYA, else
// f32-read + BN/lrelu/cvt transform in regs.
// APPLYA (KK>0): block self-finalizes prev BN from partPrev into LDS ssl.
// STATS: column sums/sumsq -> atomicAdd into partOut (zeroed in prep).
template<int BM, int BN, int WROWS, int WCOLS, int RT, int CT, bool APPLYA, bool STATS, int KK>
__global__ __launch_bounds__(WROWS*WCOLS*64)
void gemm_nt(const u16* __restrict__ A, const float* __restrict__ Af,
             const u16* __restrict__ W, float* __restrict__ Y,
             const float* __restrict__ partPrev, const float* __restrict__ gP,
             const float* __restrict__ beP, float* __restrict__ partOut,
             long YS, int M, int N, int K)
{
  constexpr int NT  = WROWS*WCOLS*64;
  constexpr int ALD = (BM*4)/NT;
  constexpr int BLD = (BN*4)/NT;
  __shared__ __align__(16) u16 As[BM*32];
  __shared__ __align__(16) u16 Bs[BN*32];
  __shared__ float ssl[APPLYA ? 2*KK : 1];
  const int tid  = threadIdx.x;
  const int wave = tid >> 6, lane = tid & 63;
  const int wr = wave / WCOLS, wc = wave % WCOLS;
  const int lrow = lane & 15, kg = lane >> 4;
  const int m0 = blockIdx.x * BM, n0 = blockIdx.y * BN;

  if constexpr (APPLYA){
    for (int k = tid; k < KK; k += NT){
      float s = partPrev[k], s2 = partPrev[KK + k];
      float inv  = 1.f / (float)M;
      float mean = s * inv;
      float var  = fmaxf(s2*inv - mean*mean, 0.f);
      float sc   = gP[k] * rsqrtf(var + 1e-5f);
      ssl[k]      = sc;
      ssl[KK + k] = beP[k] - mean*sc;
    }
    __syncthreads();
  }

  f32x4 acc[RT][CT] = {};
  for (int k0 = 0; k0 < K; k0 += 32) {
    uint4 av[ALD];
    if constexpr (APPLYA){
#pragma unroll
      for (int i = 0; i < ALD; i++){
        int x = tid + i*NT; int row = m0 + (x>>2); int c0 = k0 + (x&3)*8;
        const float* ap = Af + (size_t)row*K + c0;
        float4 f0 = *(const float4*)ap;
        float4 f1 = *(const float4*)(ap + 4);
        u32 p0 = (u32)f2b(lrelu(f0.x*ssl[c0+0] + ssl[KK+c0+0]))
               | ((u32)f2b(lrelu(f0.y*ssl[c0+1] + ssl[KK+c0+1])) << 16);
        u32 p1 = (u32)f2b(lrelu(f0.z*ssl[c0+2] + ssl[KK+c0+2]))
               | ((u32)f2b(lrelu(f0.w*ssl[c0+3] + ssl[KK+c0+3])) << 16);
        u32 p2 = (u32)f2b(lrelu(f1.x*ssl[c0+4] + ssl[KK+c0+4]))
               | ((u32)f2b(lrelu(f1.y*ssl[c0+5] + ssl[KK+c0+5])) << 16);
        u32 p3 = (u32)f2b(lrelu(f1.z*ssl[c0+6] + ssl[KK+c0+6]))
               | ((u32)f2b(lrelu(f1.w*ssl[c0+7] + ssl[KK+c0+7])) << 16);
        av[i] = uint4{p0, p1, p2, p3};
      }
    }
    __syncthreads();
    if constexpr (!APPLYA){
#pragma unroll
      for (int i = 0; i < ALD; i++){
        int x = tid + i*NT;
        gload_lds16(A + (size_t)(m0 + (x>>2))*K + k0 + (x&3)*8, As + (size_t)x*8);
      }
    }
#pragma unroll
    for (int i = 0; i < BLD; i++){
      int x = tid + i*NT;
      gload_lds16(W + (size_t)(n0 + (x>>2))*K + k0 + (x&3)*8, Bs + (size_t)x*8);
    }
    if constexpr (APPLYA){
#pragma unroll
      for (int i = 0; i < ALD; i++){ *(uint4*)(As + (tid + i*NT)*8) = av[i]; }
    }
    __syncthreads();
    short8 af[RT], bfr[CT];
#pragma unroll
    for (int r = 0; r < RT; r++) af[r]  = *(const short8*)(As + ((wr*RT + r)*16 + lrow)*32 + kg*8);
#pragma unroll
    for (int c = 0; c < CT; c++) bfr[c] = *(const short8*)(Bs + ((wc*CT + c)*16 + lrow)*32 + kg*8);
#pragma unroll
    for (int r = 0; r < RT; r++)
#pragma unroll
      for (int c = 0; c < CT; c++)
        acc[r][c] = __builtin_amdgcn_mfma_f32_16x16x32_bf16(af[r], bfr[c], acc[r][c], 0, 0, 0);
  }
  // C/D: col=lane&15, row=(lane>>4)*4+i  [m89/m91]
#pragma unroll
  for (int r = 0; r < RT; r++)
#pragma unroll
    for (int c = 0; c < CT; c++)
#pragma unroll
      for (int i = 0; i < 4; i++){
        int m = m0 + (wr*RT + r)*16 + kg*4 + i;
        int n = n0 + (wc*CT + c)*16 + lrow;
        Y[(size_t)m*YS + n] = acc[r][c][i];
      }

  if constexpr (STATS){
    __shared__ float cs[BN], cs2[BN];
    for (int t = tid; t < BN; t += NT){ cs[t] = 0.f; cs2[t] = 0.f; }
    __syncthreads();
#pragma unroll
    for (int c = 0; c < CT; c++){
      float ls = 0.f, ls2 = 0.f;
#pragma unroll
      for (int r = 0; r < RT; r++)
#pragma unroll
        for (int i = 0; i < 4; i++){ float v = acc[r][c][i]; ls += v; ls2 += v*v; }
      ls  += __shfl_down(ls, 32);  ls  += __shfl_down(ls, 16);
      ls2 += __shfl_down(ls2, 32); ls2 += __shfl_down(ls2, 16);
      if (lane < 16){
        atomicAdd(&cs [(wc*CT + c)*16 + lrow], ls);
        atomicAdd(&cs2[(wc*CT + c)*16 + lrow], ls2);
      }
    }
    __syncthreads();
    for (int t = tid; t < BN; t += NT){
      atomicAdd(partOut + n0 + t,     cs[t]);
      atomicAdd(partOut + N + n0 + t, cs2[t]);
    }
  }
}

// ---------------- fused conv1+conv2+conv3 (+BN4-in, +norms, LDS chaining) --
// Block = S samples, 8 waves. All intermediates live in LDS (no Xc2/Xc3).
// S=1: LDS ~62KB -> 2 blocks/CU; per-wave MFMA structure unchanged vs S=2
// (same waves/RT/LDS-reads-per-MFMA) — the clean occupancy experiment.
// Block b reads only its own Yf slices and writes only its own output slices;
// input fully staged before any output write -> race-free.
template<int S>
__global__ __launch_bounds__(512, (S==1) ? 4 : 2)
void conv_fused(const float* __restrict__ Yf,
                const float* __restrict__ part4,
                const float* __restrict__ g4, const float* __restrict__ be4,
                const u16* __restrict__ Wr1, const float* __restrict__ cb1,
                const u16* __restrict__ Wr2, const float* __restrict__ cb2,
                const u16* __restrict__ Wr3, const float* __restrict__ cb3,
                const int* __restrict__ gidx,
                float* __restrict__ Outf)
{
  // per-sample strides (u16): xs1 65*72, xs2 65*136, xs3 65*264
  __shared__ __align__(16) u16 xs1[S*4680];
  __shared__ __align__(16) u16 xs2[S*8840];
  __shared__ __align__(16) u16 xs3[S*17160];
  __shared__ int idxs[S*192];
  __shared__ float red[S*16];
  __shared__ float res[S*2];
  float* ssl = (float*)xs3;            // 8192 f32 = 16384 u16 < 16896 (zero-row) ok
  const int b0 = blockIdx.x * S, tid = threadIdx.x;
  const int wave = tid >> 6, lane = tid & 63;
  const int lrow = lane & 15, kg = lane >> 4;

  // phase0: BN4 scale/shift
  for (int k = tid; k < 4096; k += 512){
    float s = part4[k], s2 = part4[4096 + k];
    float inv  = 1.f / 2048.f;
    float mean = s * inv;
    float var  = fmaxf(s2*inv - mean*mean, 0.f);
    float sc   = g4[k] * rsqrtf(var + 1e-5f);
    ssl[k]        = sc;
    ssl[4096 + k] = be4[k] - mean*sc;
  }
  __syncthreads();

  // phase1: stage conv1 input (BN+lrelu+bf16+transpose), zero rows, idxs
#pragma unroll
  for (int s = 0; s < S; s++){
    const float* yg = Yf + (size_t)(b0 + s)*32768;
    u16* xd = xs1 + s*4680;
    for (int q = tid; q < 1024; q += 512){
      int j = q*4;                       // ch = c*64+n, n%4==0
      float4 v = *(const float4*)(yg + j);
      int c = j >> 6, n = j & 63;
      xd[(n+0)*72 + c] = f2b(lrelu(v.x*ssl[j+0] + ssl[4096+j+0]));
      xd[(n+1)*72 + c] = f2b(lrelu(v.y*ssl[j+1] + ssl[4096+j+1]));
      xd[(n+2)*72 + c] = f2b(lrelu(v.z*ssl[j+2] + ssl[4096+j+2]));
      xd[(n+3)*72 + c] = f2b(lrelu(v.w*ssl[j+3] + ssl[4096+j+3]));
    }
    uint4 z = {0,0,0,0};
    if (tid < 8)  *(uint4*)(xd + 64*72 + tid*8) = z;                 // xs1 row64
    if (tid < 16) *(uint4*)(xs2 + s*8840  + 64*136 + tid*8) = z;     // xs2 row64
    if (tid < 32) *(uint4*)(xs3 + s*17160 + 64*264 + tid*8) = z;     // xs3 row64 (beyond ssl)
    if (tid < 189) idxs[s*192 + tid] = gidx[(size_t)(b0 + s)*189 + tid] & 63;
  }
  __syncthreads();

  int jtp[S][4];
#pragma unroll
  for (int s = 0; s < S; s++)
#pragma unroll
    for (int ct = 0; ct < 4; ct++){
      int n = ct*16 + lrow;
      if (n == 0) jtp[s][ct] = 64 | (64<<7) | (64<<14);
      else        jtp[s][ct] = idxs[s*192 + 3*(n-1) + 0]
                             | (idxs[s*192 + 3*(n-1) + 1] << 7)
                             | (idxs[s*192 + 3*(n-1) + 2] << 14);
    }

  // ---------------- phase2: conv1 (C=64 -> O=128, RT=1) --------------------
  {
    f32x4 acc[4][S] = {};
    const size_t wb0 = (size_t)wave*192*16 + lane*8;
#pragma unroll
    for (int k = 0; k < 3; k++){
      int rb[S][4];
#pragma unroll
      for (int s = 0; s < S; s++)
#pragma unroll
        for (int ct = 0; ct < 4; ct++)
          rb[s][ct] = s*4680 + ((jtp[s][ct] >> (7*k)) & 127)*72 + kg*8;
#pragma unroll 2
      for (int cc = 0; cc < 64; cc += 32){
        short8 af = *(const short8*)(Wr1 + wb0 + (k*64 + cc)*16);
#pragma unroll
        for (int s = 0; s < S; s++){
          short8 bfr[4];
#pragma unroll
          for (int ct = 0; ct < 4; ct++) bfr[ct] = *(const short8*)(xs1 + rb[s][ct] + cc);
#pragma unroll
          for (int ct = 0; ct < 4; ct++)
            acc[ct][s] = __builtin_amdgcn_mfma_f32_16x16x32_bf16(af, bfr[ct], acc[ct][s], 0, 0, 0);
        }
      }
    }
    float sv[S] = {}, sv2[S] = {};
#pragma unroll
    for (int i = 0; i < 4; i++){
      int o = wave*16 + kg*4 + i;
      float bias = cb1[o];
#pragma unroll
      for (int ct = 0; ct < 4; ct++){
        int n = ct*16 + lrow;
#pragma unroll
        for (int s = 0; s < S; s++){
          float v = acc[ct][s][i];
          if (n != 0) v += bias;
          acc[ct][s][i] = v;
          sv[s] += v; sv2[s] += v*v;
        }
      }
    }
#pragma unroll
    for (int s = 0; s < S; s++){
#pragma unroll
      for (int off = 32; off > 0; off >>= 1){ sv[s] += __shfl_down(sv[s], off); sv2[s] += __shfl_down(sv2[s], off); }
      if (lane == 0){ red[s*16 + wave] = sv[s]; red[s*16 + 8 + wave] = sv2[s]; }
    }
    __syncthreads();
    if (tid < S){
      float Sm = 0.f, S2 = 0.f;
      for (int w = 0; w < 8; w++){ Sm += red[tid*16 + w]; S2 += red[tid*16 + 8 + w]; }
      const float NV = 8192.f;          // 128*64
      float mean = Sm / NV;
      float var  = fmaxf(S2/NV - mean*mean, 0.f) * (NV/(NV-1.f));
      float sc   = 1.f / (sqrtf(var) + 1e-5f);
      res[tid*2 + 0] = mean; res[tid*2 + 1] = sc;
    }
    __syncthreads();
#pragma unroll
    for (int s = 0; s < S; s++){
      const float mean = res[s*2 + 0], sc = res[s*2 + 1];
      int o0 = wave*16 + kg*4;
#pragma unroll
      for (int ct = 0; ct < 4; ct++){
        int n = ct*16 + lrow;
        u16x4 pk;
#pragma unroll
        for (int i = 0; i < 4; i++) pk[i] = f2b(lrelu((acc[ct][s][i] - mean)*sc));
        *(u16x4*)(xs2 + s*8840 + n*136 + o0) = pk;
      }
    }
    __syncthreads();
  }

  // ---------------- phase3: conv2 (C=128 -> O=256, RT=2) -------------------
  {
    f32x4 acc[2][4][S] = {};
    size_t wb[2];
#pragma unroll
    for (int r = 0; r < 2; r++) wb[r] = (size_t)(wave + 8*r)*384*16 + lane*8;
#pragma unroll
    for (int k = 0; k < 3; k++){
      int rb[S][4];
#pragma unroll
      for (int s = 0; s < S; s++)
#pragma unroll
        for (int ct = 0; ct < 4; ct++)
          rb[s][ct] = s*8840 + ((jtp[s][ct] >> (7*k)) & 127)*136 + kg*8;
#pragma unroll 2
      for (int cc = 0; cc < 128; cc += 32){
        const int choff = (k*128 + cc)*16;
        short8 af[2];
#pragma unroll
        for (int r = 0; r < 2; r++) af[r] = *(const short8*)(Wr2 + wb[r] + choff);
#pragma unroll
        for (int s = 0; s < S; s++){
          short8 bfr[4];
#pragma unroll
          for (int ct = 0; ct < 4; ct++) bfr[ct] = *(const short8*)(xs2 + rb[s][ct] + cc);
#pragma unroll
          for (int r = 0; r < 2; r++)
#pragma unroll
            for (int ct = 0; ct < 4; ct++)
              acc[r][ct][s] = __builtin_amdgcn_mfma_f32_16x16x32_bf16(af[r], bfr[ct], acc[r][ct][s], 0, 0, 0);
        }
      }
    }
    float sv[S] = {}, sv2[S] = {};
#pragma unroll
    for (int r = 0; r < 2; r++)
#pragma unroll
      for (int i = 0; i < 4; i++){
        int o = (wave + 8*r)*16 + kg*4 + i;
        float bias = cb2[o];
#pragma unroll
        for (int ct = 0; ct < 4; ct++){
          int n = ct*16 + lrow;
#pragma unroll
          for (int s = 0; s < S; s++){
            float v = acc[r][ct][s][i];
            if (n != 0) v += bias;
            acc[r][ct][s][i] = v;
            sv[s] += v; sv2[s] += v*v;
          }
        }
      }
#pragma unroll
    for (int s = 0; s < S; s++){
#pragma unroll
      for (int off = 32; off > 0; off >>= 1){ sv[s] += __shfl_down(sv[s], off); sv2[s] += __shfl_down(sv2[s], off); }
      if (lane == 0){ red[s*16 + wave] = sv[s]; red[s*16 + 8 + wave] = sv2[s]; }
    }
    __syncthreads();
    if (tid < S){
      float Sm = 0.f, S2 = 0.f;
      for (int w = 0; w < 8; w++){ Sm += red[tid*16 + w]; S2 += red[tid*16 + 8 + w]; }
      const float NV = 16384.f;         // 256*64
      float mean = Sm / NV;
      float var  = fmaxf(S2/NV - mean*mean, 0.f) * (NV/(NV-1.f));
      float sc   = 1.f / (sqrtf(var) + 1e-5f);
      res[tid*2 + 0] = mean; res[tid*2 + 1] = sc;
    }
    __syncthreads();
#pragma unroll
    for (int s = 0; s < S; s++){
      const float mean = res[s*2 + 0], sc = res[s*2 + 1];
#pragma unroll
      for (int r = 0; r < 2; r++)
#pragma unroll
        for (int ct = 0; ct < 4; ct++){
          int o0 = (wave + 8*r)*16 + kg*4;
          int n  = ct*16 + lrow;
          u16x4 pk;
#pragma unroll
          for (int i = 0; i < 4; i++) pk[i] = f2b(lrelu((acc[r][ct][s][i] - mean)*sc));
          *(u16x4*)(xs3 + s*17160 + n*264 + o0) = pk;
        }
    }
    __syncthreads();
  }

  // ---------------- phase4: conv3 (C=256 -> O=512, RT=4, f32 out) ----------
  {
    f32x4 acc[4][4][S] = {};
    size_t wb[4];
#pragma unroll
    for (int r = 0; r < 4; r++) wb[r] = (size_t)(wave + 8*r)*768*16 + lane*8;
#pragma unroll
    for (int k = 0; k < 3; k++){
      int rb[S][4];
#pragma unroll
      for (int s = 0; s < S; s++)
#pragma unroll
        for (int ct = 0; ct < 4; ct++)
          rb[s][ct] = s*17160 + ((jtp[s][ct] >> (7*k)) & 127)*264 + kg*8;
#pragma unroll 2
      for (int cc = 0; cc < 256; cc += 32){
        const int choff = (k*256 + cc)*16;
        short8 af[4];
#pragma unroll
        for (int r = 0; r < 4; r++) af[r] = *(const short8*)(Wr3 + wb[r] + choff);
#pragma unroll
        for (int s = 0; s < S; s++){
          short8 bfr[4];
#pragma unroll
          for (int ct = 0; ct < 4; ct++) bfr[ct] = *(const short8*)(xs3 + rb[s][ct] + cc);
#pragma unroll
          for (int r = 0; r < 4; r++)
#pragma unroll
            for (int ct = 0; ct < 4; ct++)
              acc[r][ct][s] = __builtin_amdgcn_mfma_f32_16x16x32_bf16(af[r], bfr[ct], acc[r][ct][s], 0, 0, 0);
        }
      }
    }
    float sv[S] = {}, sv2[S] = {};
#pragma unroll
    for (int r = 0; r < 4; r++)
#pragma unroll
      for (int i = 0; i < 4; i++){
        int o = (wave + 8*r)*16 + kg*4 + i;
        float bias = cb3[o];
#pragma unroll
        for (int ct = 0; ct < 4; ct++){
          int n = ct*16 + lrow;
#pragma unroll
          for (int s = 0; s < S; s++){
            float v = acc[r][ct][s][i];
            if (n != 0) v += bias;
            acc[r][ct][s][i] = v;
            sv[s] += v; sv2[s] += v*v;
          }
        }
      }
#pragma unroll
    for (int s = 0; s < S; s++){
#pragma unroll
      for (int off = 32; off > 0; off >>= 1){ sv[s] += __shfl_down(sv[s], off); sv2[s] += __shfl_down(sv2[s], off); }
      if (lane == 0){ red[s*16 + wave] = sv[s]; red[s*16 + 8 + wave] = sv2[s]; }
    }
    __syncthreads();
    if (tid < S){
      float Sm = 0.f, S2 = 0.f;
      for (int w = 0; w < 8; w++){ Sm += red[tid*16 + w]; S2 += red[tid*16 + 8 + w]; }
      const float NV = 32768.f;         // 512*64
      float mean = Sm / NV;
      float var  = fmaxf(S2/NV - mean*mean, 0.f) * (NV/(NV-1.f));
      float sc   = 1.f / (sqrtf(var) + 1e-5f);
      res[tid*2 + 0] = mean; res[tid*2 + 1] = sc;
    }
    __syncthreads();
#pragma unroll
    for (int s = 0; s < S; s++){
      const float mean = res[s*2 + 0], sc = res[s*2 + 1];
#pragma unroll
      for (int r = 0; r < 4; r++)
#pragma unroll
        for (int ct = 0; ct < 4; ct++)
#pragma unroll
          for (int i = 0; i < 4; i++){
            int o = (wave + 8*r)*16 + kg*4 + i;
            int n = ct*16 + lrow;
            Outf[(size_t)(b0 + s)*32768 + o*64 + n] = lrelu((acc[r][ct][s][i] - mean)*sc);
          }
    }
  }
}

// ---------------------------------------------------------------------------
extern "C" void kernel_launch(void* const* d_in, const int* in_sizes, int n_in,
                              void* d_out, int out_size, void* d_ws, size_t ws_size,
                              hipStream_t stream)
{
  // ALL float inputs are float32 (proven by R3's dtype-flag experiment).
  const float* trees = (const float*)d_in[0];
  const int*   gidx  = (const int*)d_in[1];
  const float* w1 = (const float*)d_in[2];
  const float* g1 = (const float*)d_in[4];  const float* be1 = (const float*)d_in[5];
  const float* w2 = (const float*)d_in[6];
  const float* g2 = (const float*)d_in[8];  const float* be2 = (const float*)d_in[9];
  const float* w3 = (const float*)d_in[10];
  const float* g3 = (const float*)d_in[12]; const float* be3 = (const float*)d_in[13];
  const float* w4 = (const float*)d_in[14];
  const float* g4 = (const float*)d_in[16]; const float* be4 = (const float*)d_in[17];
  const float* cw1 = (const float*)d_in[18]; const float* cb1 = (const float*)d_in[19];
  const float* cw2 = (const float*)d_in[20]; const float* cb2 = (const float*)d_in[21];
  const float* cw3 = (const float*)d_in[22]; const float* cb3 = (const float*)d_in[23];
  // linear biases b1..b4 cancel under training-mode BN — unused.

  // ws (~21 MiB): ALL MLP scratch + conv weights. d_out holds ONLY the gemm4
  // per-sample output slices + the final output (trivial aliasing).
  char* ws = (char*)d_ws;
  size_t off = 0;
  auto alloc = [&](size_t bytes)->char*{ char* p = ws + off; off += (bytes + 255) & ~(size_t)255; return p; };
  u16*   Wr1  = (u16*)  alloc(128*192*2);
  u16*   Wr2  = (u16*)  alloc(256*384*2);
  u16*   Wr3  = (u16*)  alloc(512*768*2);
  float* partA= (float*)alloc(2*(64+256+1024+4096)*4);
  u16*   Tb   = (u16*)  alloc(2048*64*2);
  u16*   Wb1  = (u16*)  alloc(64*64*2);
  u16*   Wb2  = (u16*)  alloc(256*64*2);
  u16*   Wb3  = (u16*)  alloc(1024*256*2);
  u16*   Wb4  = (u16*)  alloc((size_t)4096*1024*2);
  float* Ya   = (float*)alloc((size_t)2048*1024*4);   // gemm1 out / gemm3 out
  float* Yb2  = (float*)alloc((size_t)2048*256*4);    // gemm2 out
  float* part1 = partA;             // 128 floats
  float* part2 = part1 + 2*64;      // 512
  float* part3 = part2 + 2*256;     // 2048
  float* part4 = part3 + 2*1024;    // 8192

  // d_out (256 MiB): gemm4 writes sample b's pre-BN row into slice b at
  // float-offset 16384 (bytes [64K,80K) of the 128K slice); conv_fused block
  // reads its own slices' Yb, then overwrites those slices with final output.
  float* outF = (float*)d_out;
  float* Ybs  = (float*)d_out + 16384;       // slice-strided gemm4 output

  prep<<<6559, 256, 0, stream>>>(partA,
                                 trees, Tb, w1, Wb1, w2, Wb2, w3, Wb3, w4, Wb4,
                                 cw1, Wr1, cw2, Wr2, cw3, Wr3);

  // MLP: gemm(+stats) -> gemm(+selfFinalize+applyA+stats) -> ...
  gemm_nt<64,64,4,1,1,4,false,true,0><<<dim3(32,1), 256, 0, stream>>>(
      Tb, nullptr, Wb1, Ya, nullptr, nullptr, nullptr, part1, 64, 2048, 64, 64);
  gemm_nt<64,64,4,1,1,4,true,true,64><<<dim3(32,4), 256, 0, stream>>>(
      nullptr, Ya, Wb2, Yb2, part1, g1, be1, part2, 256, 2048, 256, 64);
  gemm_nt<64,64,4,1,1,4,true,true,256><<<dim3(32,16), 256, 0, stream>>>(
      nullptr, Yb2, Wb3, Ya, part2, g2, be2, part3, 1024, 2048, 1024, 256);
  gemm_nt<128,256,2,4,4,4,true,true,1024><<<dim3(16,16), 512, 0, stream>>>(
      nullptr, Ya, Wb4, Ybs, part3, g3, be3, part4, 32768, 2048, 4096, 1024);

  // fused conv stack: one kernel, intermediates in LDS.
  // S=1: LDS ~62KB -> 2 blocks/CU (clean occupancy experiment, R18).
  conv_fused<1><<<2048, 512, 0, stream>>>(Ybs, part4, g4, be4,
                                          Wr1, cb1, Wr2, cb2, Wr3, cb3,
                                          gidx, outF);
}

// Round 19
// 522.572 us; speedup vs baseline: 1.0346x; 1.0346x over previous
//
#include <hip/hip_runtime.h>

typedef unsigned short u16;
typedef unsigned int   u32;
typedef __attribute__((ext_vector_type(8))) short short8;
typedef __attribute__((ext_vector_type(4))) float f32x4;
typedef __attribute__((ext_vector_type(4))) u16  u16x4;

#define DI __device__ __forceinline__

DI float b2f(u16 v){ return __builtin_bit_cast(float, (u32)v << 16); }
DI u16 f2b(float f){ u32 u = __builtin_bit_cast(u32, f); return (u16)((u + 0x7fffu + ((u >> 16) & 1u)) >> 16); }
DI float lrelu(float v){ return v > 0.f ? v : 0.01f * v; }

// direct global->LDS DMA, 16 B per lane (dest must be lane-contiguous)
DI void gload_lds16(const void* g, void* l){
  __builtin_amdgcn_global_load_lds((const __attribute__((address_space(1))) void*)g,
                                   (__attribute__((address_space(3))) void*)l, 16, 0, 0);
}

// ---------------- prep: zero BN accumulators + f32->bf16 cvt + conv repack -
// Conv weights in MFMA-FRAGMENT-TILED layout (R10: coalesced wave loads).
__global__ __launch_bounds__(256)
void prep(float* __restrict__ partA,
          const float* __restrict__ trees, u16* __restrict__ Tb,
          const float* __restrict__ w1, u16* __restrict__ Wb1,
          const float* __restrict__ w2, u16* __restrict__ Wb2,
          const float* __restrict__ w3, u16* __restrict__ Wb3,
          const float* __restrict__ w4, u16* __restrict__ Wb4,
          const float* __restrict__ cw1, u16* __restrict__ Wr1,
          const float* __restrict__ cw2, u16* __restrict__ Wr2,
          const float* __restrict__ cw3, u16* __restrict__ Wr3)
{
  int loc = blockIdx.x*256 + threadIdx.x;
  if (loc < 10880){ partA[loc] = 0.f; return; }
  loc -= 10880;
  {
    const float* in = nullptr; u16* out = nullptr;
    if      (loc < 32768){ in = trees; out = Tb; }
    else if ((loc -= 32768) < 1024){ in = w1; out = Wb1; }
    else if ((loc -= 1024) < 4096){ in = w2; out = Wb2; }
    else if ((loc -= 4096) < 65536){ in = w3; out = Wb3; }
    else if ((loc -= 65536) < 1048576){ in = w4; out = Wb4; }
    else { loc -= 1048576; goto repack; }
    float4 v = ((const float4*)in)[loc];
    u16x4 o; o[0]=f2b(v.x); o[1]=f2b(v.y); o[2]=f2b(v.z); o[3]=f2b(v.w);
    *(u16x4*)(out + (size_t)loc*4) = o;
    return;
  }
repack:
  {
    const float* w; u16* wr; int C, lgC;
    if      (loc < 24576){ w = cw1; wr = Wr1; C = 64;  lgC = 6; }
    else if ((loc -= 24576) < 98304){ w = cw2; wr = Wr2; C = 128; lgC = 7; }
    else if ((loc -= 98304) < 393216){ w = cw3; wr = Wr3; C = 256; lgC = 8; }
    else return;
    int R   = 3*C;
    int nkb = R >> 5;                 // R/32
    int ci   = loc & 7;
    int lane = (loc >> 3) & 63;
    int blk  = loc >> 9;
    int o_tile = blk / nkb;
    int kbi    = blk - o_tile*nkb;
    int o  = o_tile*16 + (lane & 15);
    int ch = kbi*32 + (lane >> 4)*8 + ci;
    int k  = ch >> lgC;
    int c  = ch & (C-1);
    wr[loc] = f2b(w[(size_t)o*R + c*3 + k]);
  }
}

// ---------------- GEMM (NT): Y[m*YS+n] = A[M,K] * W[N,K]^T, f32 out --------
// YS: output row stride in floats (gemm4 writes per-sample d_out slices).
// Staging: B always via global_load_lds; A via DMA when !APPLYA, else
// f32-read + BN/lrelu/cvt transform in regs.
// APPLYA (KK>0): block self-finalizes prev BN from partPrev into LDS ssl.
// STATS: column sums/sumsq -> atomicAdd into partOut (zeroed in prep).
template<int BM, int BN, int WROWS, int WCOLS, int RT, int CT, bool APPLYA, bool STATS, int KK>
__global__ __launch_bounds__(WROWS*WCOLS*64)
void gemm_nt(const u16* __restrict__ A, const float* __restrict__ Af,
             const u16* __restrict__ W, float* __restrict__ Y,
             const float* __restrict__ partPrev, const float* __restrict__ gP,
             const float* __restrict__ beP, float* __restrict__ partOut,
             long YS, int M, int N, int K)
{
  constexpr int NT  = WROWS*WCOLS*64;
  constexpr int ALD = (BM*4)/NT;
  constexpr int BLD = (BN*4)/NT;
  __shared__ __align__(16) u16 As[BM*32];
  __shared__ __align__(16) u16 Bs[BN*32];
  __shared__ float ssl[APPLYA ? 2*KK : 1];
  const int tid  = threadIdx.x;
  const int wave = tid >> 6, lane = tid & 63;
  const int wr = wave / WCOLS, wc = wave % WCOLS;
  const int lrow = lane & 15, kg = lane >> 4;
  const int m0 = blockIdx.x * BM, n0 = blockIdx.y * BN;

  if constexpr (APPLYA){
    for (int k = tid; k < KK; k += NT){
      float s = partPrev[k], s2 = partPrev[KK + k];
      float inv  = 1.f / (float)M;
      float mean = s * inv;
      float var  = fmaxf(s2*inv - mean*mean, 0.f);
      float sc   = gP[k] * rsqrtf(var + 1e-5f);
      ssl[k]      = sc;
      ssl[KK + k] = beP[k] - mean*sc;
    }
    __syncthreads();
  }

  f32x4 acc[RT][CT] = {};
  for (int k0 = 0; k0 < K; k0 += 32) {
    uint4 av[ALD];
    if constexpr (APPLYA){
#pragma unroll
      for (int i = 0; i < ALD; i++){
        int x = tid + i*NT; int row = m0 + (x>>2); int c0 = k0 + (x&3)*8;
        const float* ap = Af + (size_t)row*K + c0;
        float4 f0 = *(const float4*)ap;
        float4 f1 = *(const float4*)(ap + 4);
        u32 p0 = (u32)f2b(lrelu(f0.x*ssl[c0+0] + ssl[KK+c0+0]))
               | ((u32)f2b(lrelu(f0.y*ssl[c0+1] + ssl[KK+c0+1])) << 16);
        u32 p1 = (u32)f2b(lrelu(f0.z*ssl[c0+2] + ssl[KK+c0+2]))
               | ((u32)f2b(lrelu(f0.w*ssl[c0+3] + ssl[KK+c0+3])) << 16);
        u32 p2 = (u32)f2b(lrelu(f1.x*ssl[c0+4] + ssl[KK+c0+4]))
               | ((u32)f2b(lrelu(f1.y*ssl[c0+5] + ssl[KK+c0+5])) << 16);
        u32 p3 = (u32)f2b(lrelu(f1.z*ssl[c0+6] + ssl[KK+c0+6]))
               | ((u32)f2b(lrelu(f1.w*ssl[c0+7] + ssl[KK+c0+7])) << 16);
        av[i] = uint4{p0, p1, p2, p3};
      }
    }
    __syncthreads();
    if constexpr (!APPLYA){
#pragma unroll
      for (int i = 0; i < ALD; i++){
        int x = tid + i*NT;
        gload_lds16(A + (size_t)(m0 + (x>>2))*K + k0 + (x&3)*8, As + (size_t)x*8);
      }
    }
#pragma unroll
    for (int i = 0; i < BLD; i++){
      int x = tid + i*NT;
      gload_lds16(W + (size_t)(n0 + (x>>2))*K + k0 + (x&3)*8, Bs + (size_t)x*8);
    }
    if constexpr (APPLYA){
#pragma unroll
      for (int i = 0; i < ALD; i++){ *(uint4*)(As + (tid + i*NT)*8) = av[i]; }
    }
    __syncthreads();
    short8 af[RT], bfr[CT];
#pragma unroll
    for (int r = 0; r < RT; r++) af[r]  = *(const short8*)(As + ((wr*RT + r)*16 + lrow)*32 + kg*8);
#pragma unroll
    for (int c = 0; c < CT; c++) bfr[c] = *(const short8*)(Bs + ((wc*CT + c)*16 + lrow)*32 + kg*8);
#pragma unroll
    for (int r = 0; r < RT; r++)
#pragma unroll
      for (int c = 0; c < CT; c++)
        acc[r][c] = __builtin_amdgcn_mfma_f32_16x16x32_bf16(af[r], bfr[c], acc[r][c], 0, 0, 0);
  }
  // C/D: col=lane&15, row=(lane>>4)*4+i  [m89/m91]
#pragma unroll
  for (int r = 0; r < RT; r++)
#pragma unroll
    for (int c = 0; c < CT; c++)
#pragma unroll
      for (int i = 0; i < 4; i++){
        int m = m0 + (wr*RT + r)*16 + kg*4 + i;
        int n = n0 + (wc*CT + c)*16 + lrow;
        Y[(size_t)m*YS + n] = acc[r][c][i];
      }

  if constexpr (STATS){
    __shared__ float cs[BN], cs2[BN];
    for (int t = tid; t < BN; t += NT){ cs[t] = 0.f; cs2[t] = 0.f; }
    __syncthreads();
#pragma unroll
    for (int c = 0; c < CT; c++){
      float ls = 0.f, ls2 = 0.f;
#pragma unroll
      for (int r = 0; r < RT; r++)
#pragma unroll
        for (int i = 0; i < 4; i++){ float v = acc[r][c][i]; ls += v; ls2 += v*v; }
      ls  += __shfl_down(ls, 32);  ls  += __shfl_down(ls, 16);
      ls2 += __shfl_down(ls2, 32); ls2 += __shfl_down(ls2, 16);
      if (lane < 16){
        atomicAdd(&cs [(wc*CT + c)*16 + lrow], ls);
        atomicAdd(&cs2[(wc*CT + c)*16 + lrow], ls2);
      }
    }
    __syncthreads();
    for (int t = tid; t < BN; t += NT){
      atomicAdd(partOut + n0 + t,     cs[t]);
      atomicAdd(partOut + N + n0 + t, cs2[t]);
    }
  }
}

// ---------------- fused conv1+conv2+conv3 (+BN4-in, +norms, LDS chaining) --
// Block = S samples, 8 waves. All intermediates live in LDS (no Xc2/Xc3):
//   phase0: self-finalize BN4 -> ssl (overlaid on xs3 storage, dead later)
//   phase1: stage conv1 input from Yf slices (BN+lrelu+bf16+transpose) -> xs1
//   phase2: conv1 MFMA + TreeLayerNorm -> xs2 (bf16, node-major, CSI=136)
//   phase3: conv2 MFMA + TreeLayerNorm -> xs3 (bf16, node-major, CSI=264)
//   phase4: conv3 MFMA + TreeLayerNorm -> Outf slice (f32, o*64+n)
// S=2 is reuse-optimal (R18: S=1 doubled occupancy to 43% but regressed —
// weight-stream reuse beats TLP; the kernel is stream/gather-bound).
// Block b reads only its own Yf slices and writes only its own output slices;
// input fully staged before any output write -> race-free.
template<int S>
__global__ __launch_bounds__(512, (S==1) ? 4 : 2)
void conv_fused(const float* __restrict__ Yf,
                const float* __restrict__ part4,
                const float* __restrict__ g4, const float* __restrict__ be4,
                const u16* __restrict__ Wr1, const float* __restrict__ cb1,
                const u16* __restrict__ Wr2, const float* __restrict__ cb2,
                const u16* __restrict__ Wr3, const float* __restrict__ cb3,
                const int* __restrict__ gidx,
                float* __restrict__ Outf)
{
  // per-sample strides (u16): xs1 65*72, xs2 65*136, xs3 65*264
  __shared__ __align__(16) u16 xs1[S*4680];
  __shared__ __align__(16) u16 xs2[S*8840];
  __shared__ __align__(16) u16 xs3[S*17160];
  __shared__ int idxs[S*192];
  __shared__ float red[S*16];
  __shared__ float res[S*2];
  float* ssl = (float*)xs3;            // 8192 f32 = 16384 u16 < 16896 (zero-row) ok
  const int b0 = blockIdx.x * S, tid = threadIdx.x;
  const int wave = tid >> 6, lane = tid & 63;
  const int lrow = lane & 15, kg = lane >> 4;

  // phase0: BN4 scale/shift
  for (int k = tid; k < 4096; k += 512){
    float s = part4[k], s2 = part4[4096 + k];
    float inv  = 1.f / 2048.f;
    float mean = s * inv;
    float var  = fmaxf(s2*inv - mean*mean, 0.f);
    float sc   = g4[k] * rsqrtf(var + 1e-5f);
    ssl[k]        = sc;
    ssl[4096 + k] = be4[k] - mean*sc;
  }
  __syncthreads();

  // phase1: stage conv1 input (BN+lrelu+bf16+transpose), zero rows, idxs
#pragma unroll
  for (int s = 0; s < S; s++){
    const float* yg = Yf + (size_t)(b0 + s)*32768;
    u16* xd = xs1 + s*4680;
    for (int q = tid; q < 1024; q += 512){
      int j = q*4;                       // ch = c*64+n, n%4==0
      float4 v = *(const float4*)(yg + j);
      int c = j >> 6, n = j & 63;
      xd[(n+0)*72 + c] = f2b(lrelu(v.x*ssl[j+0] + ssl[4096+j+0]));
      xd[(n+1)*72 + c] = f2b(lrelu(v.y*ssl[j+1] + ssl[4096+j+1]));
      xd[(n+2)*72 + c] = f2b(lrelu(v.z*ssl[j+2] + ssl[4096+j+2]));
      xd[(n+3)*72 + c] = f2b(lrelu(v.w*ssl[j+3] + ssl[4096+j+3]));
    }
    uint4 z = {0,0,0,0};
    if (tid < 8)  *(uint4*)(xd + 64*72 + tid*8) = z;                 // xs1 row64
    if (tid < 16) *(uint4*)(xs2 + s*8840  + 64*136 + tid*8) = z;     // xs2 row64
    if (tid < 32) *(uint4*)(xs3 + s*17160 + 64*264 + tid*8) = z;     // xs3 row64 (beyond ssl)
    if (tid < 189) idxs[s*192 + tid] = gidx[(size_t)(b0 + s)*189 + tid] & 63;
  }
  __syncthreads();

  int jtp[S][4];
#pragma unroll
  for (int s = 0; s < S; s++)
#pragma unroll
    for (int ct = 0; ct < 4; ct++){
      int n = ct*16 + lrow;
      if (n == 0) jtp[s][ct] = 64 | (64<<7) | (64<<14);
      else        jtp[s][ct] = idxs[s*192 + 3*(n-1) + 0]
                             | (idxs[s*192 + 3*(n-1) + 1] << 7)
                             | (idxs[s*192 + 3*(n-1) + 2] << 14);
    }

  // ---------------- phase2: conv1 (C=64 -> O=128, RT=1) --------------------
  {
    f32x4 acc[4][S] = {};
    const size_t wb0 = (size_t)wave*192*16 + lane*8;
#pragma unroll
    for (int k = 0; k < 3; k++){
      int rb[S][4];
#pragma unroll
      for (int s = 0; s < S; s++)
#pragma unroll
        for (int ct = 0; ct < 4; ct++)
          rb[s][ct] = s*4680 + ((jtp[s][ct] >> (7*k)) & 127)*72 + kg*8;
#pragma unroll 2
      for (int cc = 0; cc < 64; cc += 32){
        short8 af = *(const short8*)(Wr1 + wb0 + (k*64 + cc)*16);
#pragma unroll
        for (int s = 0; s < S; s++){
          short8 bfr[4];
#pragma unroll
          for (int ct = 0; ct < 4; ct++) bfr[ct] = *(const short8*)(xs1 + rb[s][ct] + cc);
#pragma unroll
          for (int ct = 0; ct < 4; ct++)
            acc[ct][s] = __builtin_amdgcn_mfma_f32_16x16x32_bf16(af, bfr[ct], acc[ct][s], 0, 0, 0);
        }
      }
    }
    float sv[S] = {}, sv2[S] = {};
#pragma unroll
    for (int i = 0; i < 4; i++){
      int o = wave*16 + kg*4 + i;
      float bias = cb1[o];
#pragma unroll
      for (int ct = 0; ct < 4; ct++){
        int n = ct*16 + lrow;
#pragma unroll
        for (int s = 0; s < S; s++){
          float v = acc[ct][s][i];
          if (n != 0) v += bias;
          acc[ct][s][i] = v;
          sv[s] += v; sv2[s] += v*v;
        }
      }
    }
#pragma unroll
    for (int s = 0; s < S; s++){
#pragma unroll
      for (int off = 32; off > 0; off >>= 1){ sv[s] += __shfl_down(sv[s], off); sv2[s] += __shfl_down(sv2[s], off); }
      if (lane == 0){ red[s*16 + wave] = sv[s]; red[s*16 + 8 + wave] = sv2[s]; }
    }
    __syncthreads();
    if (tid < S){
      float Sm = 0.f, S2 = 0.f;
      for (int w = 0; w < 8; w++){ Sm += red[tid*16 + w]; S2 += red[tid*16 + 8 + w]; }
      const float NV = 8192.f;          // 128*64
      float mean = Sm / NV;
      float var  = fmaxf(S2/NV - mean*mean, 0.f) * (NV/(NV-1.f));
      float sc   = 1.f / (sqrtf(var) + 1e-5f);
      res[tid*2 + 0] = mean; res[tid*2 + 1] = sc;
    }
    __syncthreads();
#pragma unroll
    for (int s = 0; s < S; s++){
      const float mean = res[s*2 + 0], sc = res[s*2 + 1];
      int o0 = wave*16 + kg*4;
#pragma unroll
      for (int ct = 0; ct < 4; ct++){
        int n = ct*16 + lrow;
        u16x4 pk;
#pragma unroll
        for (int i = 0; i < 4; i++) pk[i] = f2b(lrelu((acc[ct][s][i] - mean)*sc));
        *(u16x4*)(xs2 + s*8840 + n*136 + o0) = pk;
      }
    }
    __syncthreads();
  }

  // ---------------- phase3: conv2 (C=128 -> O=256, RT=2) -------------------
  {
    f32x4 acc[2][4][S] = {};
    size_t wb[2];
#pragma unroll
    for (int r = 0; r < 2; r++) wb[r] = (size_t)(wave + 8*r)*384*16 + lane*8;
#pragma unroll
    for (int k = 0; k < 3; k++){
      int rb[S][4];
#pragma unroll
      for (int s = 0; s < S; s++)
#pragma unroll
        for (int ct = 0; ct < 4; ct++)
          rb[s][ct] = s*8840 + ((jtp[s][ct] >> (7*k)) & 127)*136 + kg*8;
#pragma unroll 2
      for (int cc = 0; cc < 128; cc += 32){
        const int choff = (k*128 + cc)*16;
        short8 af[2];
#pragma unroll
        for (int r = 0; r < 2; r++) af[r] = *(const short8*)(Wr2 + wb[r] + choff);
#pragma unroll
        for (int s = 0; s < S; s++){
          short8 bfr[4];
#pragma unroll
          for (int ct = 0; ct < 4; ct++) bfr[ct] = *(const short8*)(xs2 + rb[s][ct] + cc);
#pragma unroll
          for (int r = 0; r < 2; r++)
#pragma unroll
            for (int ct = 0; ct < 4; ct++)
              acc[r][ct][s] = __builtin_amdgcn_mfma_f32_16x16x32_bf16(af[r], bfr[ct], acc[r][ct][s], 0, 0, 0);
        }
      }
    }
    float sv[S] = {}, sv2[S] = {};
#pragma unroll
    for (int r = 0; r < 2; r++)
#pragma unroll
      for (int i = 0; i < 4; i++){
        int o = (wave + 8*r)*16 + kg*4 + i;
        float bias = cb2[o];
#pragma unroll
        for (int ct = 0; ct < 4; ct++){
          int n = ct*16 + lrow;
#pragma unroll
          for (int s = 0; s < S; s++){
            float v = acc[r][ct][s][i];
            if (n != 0) v += bias;
            acc[r][ct][s][i] = v;
            sv[s] += v; sv2[s] += v*v;
          }
        }
      }
#pragma unroll
    for (int s = 0; s < S; s++){
#pragma unroll
      for (int off = 32; off > 0; off >>= 1){ sv[s] += __shfl_down(sv[s], off); sv2[s] += __shfl_down(sv2[s], off); }
      if (lane == 0){ red[s*16 + wave] = sv[s]; red[s*16 + 8 + wave] = sv2[s]; }
    }
    __syncthreads();
    if (tid < S){
      float Sm = 0.f, S2 = 0.f;
      for (int w = 0; w < 8; w++){ Sm += red[tid*16 + w]; S2 += red[tid*16 + 8 + w]; }
      const float NV = 16384.f;         // 256*64
      float mean = Sm / NV;
      float var  = fmaxf(S2/NV - mean*mean, 0.f) * (NV/(NV-1.f));
      float sc   = 1.f / (sqrtf(var) + 1e-5f);
      res[tid*2 + 0] = mean; res[tid*2 + 1] = sc;
    }
    __syncthreads();
#pragma unroll
    for (int s = 0; s < S; s++){
      const float mean = res[s*2 + 0], sc = res[s*2 + 1];
#pragma unroll
      for (int r = 0; r < 2; r++)
#pragma unroll
        for (int ct = 0; ct < 4; ct++){
          int o0 = (wave + 8*r)*16 + kg*4;
          int n  = ct*16 + lrow;
          u16x4 pk;
#pragma unroll
          for (int i = 0; i < 4; i++) pk[i] = f2b(lrelu((acc[r][ct][s][i] - mean)*sc));
          *(u16x4*)(xs3 + s*17160 + n*264 + o0) = pk;
        }
    }
    __syncthreads();
  }

  // ---------------- phase4: conv3 (C=256 -> O=512, RT=4, f32 out) ----------
  {
    f32x4 acc[4][4][S] = {};
    size_t wb[4];
#pragma unroll
    for (int r = 0; r < 4; r++) wb[r] = (size_t)(wave + 8*r)*768*16 + lane*8;
#pragma unroll
    for (int k = 0; k < 3; k++){
      int rb[S][4];
#pragma unroll
      for (int s = 0; s < S; s++)
#pragma unroll
        for (int ct = 0; ct < 4; ct++)
          rb[s][ct] = s*17160 + ((jtp[s][ct] >> (7*k)) & 127)*264 + kg*8;
#pragma unroll 2
      for (int cc = 0; cc < 256; cc += 32){
        const int choff = (k*256 + cc)*16;
        short8 af[4];
#pragma unroll
        for (int r = 0; r < 4; r++) af[r] = *(const short8*)(Wr3 + wb[r] + choff);
#pragma unroll
        for (int s = 0; s < S; s++){
          short8 bfr[4];
#pragma unroll
          for (int ct = 0; ct < 4; ct++) bfr[ct] = *(const short8*)(xs3 + rb[s][ct] + cc);
#pragma unroll
          for (int r = 0; r < 4; r++)
#pragma unroll
            for (int ct = 0; ct < 4; ct++)
              acc[r][ct][s] = __builtin_amdgcn_mfma_f32_16x16x32_bf16(af[r], bfr[ct], acc[r][ct][s], 0, 0, 0);
        }
      }
    }
    float sv[S] = {}, sv2[S] = {};
#pragma unroll
    for (int r = 0; r < 4; r++)
#pragma unroll
      for (int i = 0; i < 4; i++){
        int o = (wave + 8*r)*16 + kg*4 + i;
        float bias = cb3[o];
#pragma unroll
        for (int ct = 0; ct < 4; ct++){
          int n = ct*16 + lrow;
#pragma unroll
          for (int s = 0; s < S; s++){
            float v = acc[r][ct][s][i];
            if (n != 0) v += bias;
            acc[r][ct][s][i] = v;
            sv[s] += v; sv2[s] += v*v;
          }
        }
      }
#pragma unroll
    for (int s = 0; s < S; s++){
#pragma unroll
      for (int off = 32; off > 0; off >>= 1){ sv[s] += __shfl_down(sv[s], off); sv2[s] += __shfl_down(sv2[s], off); }
      if (lane == 0){ red[s*16 + wave] = sv[s]; red[s*16 + 8 + wave] = sv2[s]; }
    }
    __syncthreads();
    if (tid < S){
      float Sm = 0.f, S2 = 0.f;
      for (int w = 0; w < 8; w++){ Sm += red[tid*16 + w]; S2 += red[tid*16 + 8 + w]; }
      const float NV = 32768.f;         // 512*64
      float mean = Sm / NV;
      float var  = fmaxf(S2/NV - mean*mean, 0.f) * (NV/(NV-1.f));
      float sc   = 1.f / (sqrtf(var) + 1e-5f);
      res[tid*2 + 0] = mean; res[tid*2 + 1] = sc;
    }
    __syncthreads();
#pragma unroll
    for (int s = 0; s < S; s++){
      const float mean = res[s*2 + 0], sc = res[s*2 + 1];
#pragma unroll
      for (int r = 0; r < 4; r++)
#pragma unroll
        for (int ct = 0; ct < 4; ct++)
#pragma unroll
          for (int i = 0; i < 4; i++){
            int o = (wave + 8*r)*16 + kg*4 + i;
            int n = ct*16 + lrow;
            Outf[(size_t)(b0 + s)*32768 + o*64 + n] = lrelu((acc[r][ct][s][i] - mean)*sc);
          }
    }
  }
}

// ---------------------------------------------------------------------------
extern "C" void kernel_launch(void* const* d_in, const int* in_sizes, int n_in,
                              void* d_out, int out_size, void* d_ws, size_t ws_size,
                              hipStream_t stream)
{
  // ALL float inputs are float32 (proven by R3's dtype-flag experiment).
  const float* trees = (const float*)d_in[0];
  const int*   gidx  = (const int*)d_in[1];
  const float* w1 = (const float*)d_in[2];
  const float* g1 = (const float*)d_in[4];  const float* be1 = (const float*)d_in[5];
  const float* w2 = (const float*)d_in[6];
  const float* g2 = (const float*)d_in[8];  const float* be2 = (const float*)d_in[9];
  const float* w3 = (const float*)d_in[10];
  const float* g3 = (const float*)d_in[12]; const float* be3 = (const float*)d_in[13];
  const float* w4 = (const float*)d_in[14];
  const float* g4 = (const float*)d_in[16]; const float* be4 = (const float*)d_in[17];
  const float* cw1 = (const float*)d_in[18]; const float* cb1 = (const float*)d_in[19];
  const float* cw2 = (const float*)d_in[20]; const float* cb2 = (const float*)d_in[21];
  const float* cw3 = (const float*)d_in[22]; const float* cb3 = (const float*)d_in[23];
  // linear biases b1..b4 cancel under training-mode BN — unused.

  // ws (~21 MiB): ALL MLP scratch + conv weights. d_out holds ONLY the gemm4
  // per-sample output slices + the final output (trivial aliasing).
  char* ws = (char*)d_ws;
  size_t off = 0;
  auto alloc = [&](size_t bytes)->char*{ char* p = ws + off; off += (bytes + 255) & ~(size_t)255; return p; };
  u16*   Wr1  = (u16*)  alloc(128*192*2);
  u16*   Wr2  = (u16*)  alloc(256*384*2);
  u16*   Wr3  = (u16*)  alloc(512*768*2);
  float* partA= (float*)alloc(2*(64+256+1024+4096)*4);
  u16*   Tb   = (u16*)  alloc(2048*64*2);
  u16*   Wb1  = (u16*)  alloc(64*64*2);
  u16*   Wb2  = (u16*)  alloc(256*64*2);
  u16*   Wb3  = (u16*)  alloc(1024*256*2);
  u16*   Wb4  = (u16*)  alloc((size_t)4096*1024*2);
  float* Ya   = (float*)alloc((size_t)2048*1024*4);   // gemm1 out / gemm3 out
  float* Yb2  = (float*)alloc((size_t)2048*256*4);    // gemm2 out
  float* part1 = partA;             // 128 floats
  float* part2 = part1 + 2*64;      // 512
  float* part3 = part2 + 2*256;     // 2048
  float* part4 = part3 + 2*1024;    // 8192

  // d_out (256 MiB): gemm4 writes sample b's pre-BN row into slice b at
  // float-offset 16384 (bytes [64K,80K) of the 128K slice); conv_fused block
  // reads its own slices' Yb, then overwrites those slices with final output.
  float* outF = (float*)d_out;
  float* Ybs  = (float*)d_out + 16384;       // slice-strided gemm4 output

  prep<<<6559, 256, 0, stream>>>(partA,
                                 trees, Tb, w1, Wb1, w2, Wb2, w3, Wb3, w4, Wb4,
                                 cw1, Wr1, cw2, Wr2, cw3, Wr3);

  // MLP: gemm(+stats) -> gemm(+selfFinalize+applyA+stats) -> ...
  gemm_nt<64,64,4,1,1,4,false,true,0><<<dim3(32,1), 256, 0, stream>>>(
      Tb, nullptr, Wb1, Ya, nullptr, nullptr, nullptr, part1, 64, 2048, 64, 64);
  gemm_nt<64,64,4,1,1,4,true,true,64><<<dim3(32,4), 256, 0, stream>>>(
      nullptr, Ya, Wb2, Yb2, part1, g1, be1, part2, 256, 2048, 256, 64);
  gemm_nt<64,64,4,1,1,4,true,true,256><<<dim3(32,16), 256, 0, stream>>>(
      nullptr, Yb2, Wb3, Ya, part2, g2, be2, part3, 1024, 2048, 1024, 256);
  gemm_nt<128,256,2,4,4,4,true,true,1024><<<dim3(16,16), 512, 0, stream>>>(
      nullptr, Ya, Wb4, Ybs, part3, g3, be3, part4, 32768, 2048, 4096, 1024);

  // fused conv stack: one kernel, intermediates in LDS (S=2 reuse-optimal).
  conv_fused<2><<<1024, 512, 0, stream>>>(Ybs, part4, g4, be4,
                                          Wr1, cb1, Wr2, cb2, Wr3, cb3,
                                          gidx, outF);
}